// Round 5
// baseline (52.092 us; speedup 1.0000x reference)
//
#include <hip/hip_runtime.h>
#include <hip/hip_bf16.h>
#include <stdint.h>

typedef __attribute__((ext_vector_type(8))) short bf16x8;
typedef __attribute__((ext_vector_type(4))) float f32x4;

static constexpr int B_ROWS = 2097152;
static constexpr int BLOCKS = 1024;
static constexpr int WAVES_PER_BLOCK = 4;
static constexpr int TOTAL_WAVES = BLOCKS * WAVES_PER_BLOCK;      // 4096
static constexpr int NSUPER = B_ROWS / (TOTAL_WAVES * 64);        // 8 super-tiles/wave

__device__ __forceinline__ short f2bf(float f) {
  union { float f; uint32_t u; } v; v.f = f;
  uint32_t r = v.u + 0x7fffu + ((v.u >> 16) & 1u);   // RNE truncate to bf16
  return (short)(r >> 16);
}
__device__ __forceinline__ uint32_t pk2(float lo, float hi) {
  union { __hip_bfloat162 h; uint32_t u; } v;
  v.h = __float22bfloat162_rn(float2{lo, hi});       // v_cvt_pk_bf16_f32
  return v.u;
}
__device__ __forceinline__ float relu(float x) { return x > 0.f ? x : 0.f; }

// R5: 64-row super-tiles. Dense wave-loads (lane l <-> byte 16l; 16 sectors/instr,
// 100% sector utilization) stage x_all(7168B)+x_local(1024B) into per-wave
// private LDS; swapped-MFMA compute x4; all-64-lane dense epilogue store.
// No barriers: private LDS, same-wave DS ordering covers WAR across iterations.
__global__ __launch_bounds__(256, 4) void colony_mlp(
    const float* __restrict__ x_local, const float* __restrict__ x_all,
    const float* __restrict__ W1, const float* __restrict__ b1,
    const float* __restrict__ W2, const float* __restrict__ b2,
    const float* __restrict__ W3, const float* __restrict__ b3,
    const float* __restrict__ rw, float* __restrict__ out)
{
  __shared__ char lds[WAVES_PER_BLOCK][8192];   // 7168B x_all + 1024B x_local per wave

  const int tid  = threadIdx.x;
  const int wave = tid >> 6;
  const int lane = tid & 63;
  const int c = lane & 15;   // batch-row-in-subtile (and weight-fragment col)
  const int g = lane >> 4;   // k-group
  char* ldsb = lds[wave];

  // ---- W1^T fragments (A-operand): w1f[t][j] = W1[k=8g+j][16t+c] ----
  // k=28 slot (g==3,j==4) carries b1; k=29..31 are zero.
  bf16x8 w1f[4];
#pragma unroll
  for (int t = 0; t < 4; ++t)
#pragma unroll
    for (int j = 0; j < 8; ++j) {
      int k = 8 * g + j;
      float v = (k < 28) ? W1[k * 64 + 16 * t + c]
              : (k == 28) ? b1[16 * t + c] : 0.f;
      w1f[t][j] = f2bf(v);
    }
  // ---- W2^T fragments with the layer-2 k-perm: feat = 16*(2ks+(j>>2)) + 4g + (j&3) ----
  bf16x8 w2f[2][2];   // [t2][ks]
#pragma unroll
  for (int t2 = 0; t2 < 2; ++t2)
#pragma unroll
    for (int ks = 0; ks < 2; ++ks)
#pragma unroll
      for (int j = 0; j < 8; ++j) {
        int feat = 16 * (2 * ks + (j >> 2)) + 4 * g + (j & 3);
        w2f[t2][ks][j] = f2bf(W2[feat * 32 + 16 * t2 + c]);
      }
  // per-(g,r) layer-2 bias and layer-3 weights (feat2 = 16t2 + 4g + r)
  float b2v[2][4], w3v[2][4];
#pragma unroll
  for (int t2 = 0; t2 < 2; ++t2)
#pragma unroll
    for (int r = 0; r < 4; ++r) {
      b2v[t2][r] = b2[16 * t2 + 4 * g + r];
      w3v[t2][r] = 0.1f * W3[16 * t2 + 4 * g + r];
    }

  // softmax(|risk_weights|), uniform
  const float e0 = expf(fabsf(rw[0])), e1 = expf(fabsf(rw[1]));
  const float e2 = expf(fabsf(rw[2])), e3 = expf(fabsf(rw[3]));
  const float inv = 1.f / (e0 + e1 + e2 + e3);
  const float sw0 = e0 * inv, sw1 = e1 * inv, sw2 = e2 * inv, sw3 = e3 * inv;
  const float cbase = 0.3f + 0.1f * b3[0];

  const int wave_id = blockIdx.x * WAVES_PER_BLOCK + wave;   // 0..4095

  for (int st = 0; st < NSUPER; ++st) {
    const size_t cur = (size_t)wave_id + (size_t)st * TOTAL_WAVES;  // super-tile idx
    // ---- dense staging: 8 x (64 lanes x 16B contiguous) ----
    const char* ga = (const char*)x_all + cur * 7168 + (size_t)lane * 16;
    f32x4 r0 = *(const f32x4*)(ga);
    f32x4 r1 = *(const f32x4*)(ga + 1024);
    f32x4 r2 = *(const f32x4*)(ga + 2048);
    f32x4 r3 = *(const f32x4*)(ga + 3072);
    f32x4 r4 = *(const f32x4*)(ga + 4096);
    f32x4 r5 = *(const f32x4*)(ga + 5120);
    f32x4 r6 = *(const f32x4*)(ga + 6144);
    f32x4 rl = *(const f32x4*)((const char*)x_local + cur * 1024 + (size_t)lane * 16);

    char* la = ldsb + (size_t)lane * 16;
    *(f32x4*)(la        ) = r0;
    *(f32x4*)(la + 1024) = r1;
    *(f32x4*)(la + 2048) = r2;
    *(f32x4*)(la + 3072) = r3;
    *(f32x4*)(la + 4096) = r4;
    *(f32x4*)(la + 5120) = r5;
    *(f32x4*)(la + 6144) = r6;
    *(f32x4*)(la + 7168) = rl;
    asm volatile("s_waitcnt lgkmcnt(0)" ::: "memory");

    float pout = 0.f;
#pragma unroll
    for (int s = 0; s < 4; ++s) {
      const int rowoff = (16 * s + c) * 112;   // row bytes within x_all block
      // fa: g==0 from x_local block (floats 0..3); g>=1 floats 8g..8g+3
      f32x4 ca = (g == 0) ? *(const f32x4*)(ldsb + 7168 + (16 * s + c) * 16)
                          : *(const f32x4*)(ldsb + rowoff + 32 * g);
      // fb: floats fboff..fboff+3 (g==3: dup, masked by zero weights / bias slot)
      f32x4 cb = *(const f32x4*)(ldsb + rowoff + ((g == 3) ? 64 : 32 * g + 16));

      bf16x8 af;
      uint32_t* au = (uint32_t*)&af;
      au[0] = pk2(ca.x, ca.y);
      au[1] = pk2(ca.z, ca.w);
      au[2] = (g == 3) ? 0x00003F80u : pk2(cb.x, cb.y);   // bf16(1.0) bias slot
      au[3] = pk2(cb.z, cb.w);

      f32x4 acc[4];
#pragma unroll
      for (int t = 0; t < 4; ++t) {
        f32x4 zero = {0.f, 0.f, 0.f, 0.f};
        acc[t] = __builtin_amdgcn_mfma_f32_16x16x32_bf16(w1f[t], af, zero, 0, 0, 0);
      }
      bf16x8 a2[2];
#pragma unroll
      for (int ks = 0; ks < 2; ++ks) {
        uint32_t* u = (uint32_t*)&a2[ks];
        u[0] = pk2(relu(acc[2 * ks + 0][0]), relu(acc[2 * ks + 0][1]));
        u[1] = pk2(relu(acc[2 * ks + 0][2]), relu(acc[2 * ks + 0][3]));
        u[2] = pk2(relu(acc[2 * ks + 1][0]), relu(acc[2 * ks + 1][1]));
        u[3] = pk2(relu(acc[2 * ks + 1][2]), relu(acc[2 * ks + 1][3]));
      }
      f32x4 acc2[2];
#pragma unroll
      for (int t2 = 0; t2 < 2; ++t2) {
        f32x4 ci = {b2v[t2][0], b2v[t2][1], b2v[t2][2], b2v[t2][3]};
        ci = __builtin_amdgcn_mfma_f32_16x16x32_bf16(w2f[t2][0], a2[0], ci, 0, 0, 0);
        acc2[t2] = __builtin_amdgcn_mfma_f32_16x16x32_bf16(w2f[t2][1], a2[1], ci, 0, 0, 0);
      }
      float p = 0.f;
#pragma unroll
      for (int t2 = 0; t2 < 2; ++t2)
#pragma unroll
        for (int r = 0; r < 4; ++r)
          p = fmaf(relu(acc2[t2][r]), w3v[t2][r], p);
      p += __shfl_xor(p, 16, 64);
      p += __shfl_xor(p, 32, 64);

      if (s == g) pout = p;   // lane l=(g,c) owns row 16g+c = l of this super-tile
    }

    // ---- dense epilogue: all 64 lanes; rl = x_local[R+lane] (lane-aligned) ----
    float risk = sw0 * rl.x + sw1 * rl.y + sw2 * rl.z + sw3 * rl.w;
    out[cur * 64 + lane] = cbase - risk + pout;
  }
}

extern "C" void kernel_launch(void* const* d_in, const int* in_sizes, int n_in,
                              void* d_out, int out_size, void* d_ws, size_t ws_size,
                              hipStream_t stream) {
  colony_mlp<<<dim3(BLOCKS), dim3(256), 0, stream>>>(
      (const float*)d_in[0], (const float*)d_in[1], (const float*)d_in[2],
      (const float*)d_in[3], (const float*)d_in[4], (const float*)d_in[5],
      (const float*)d_in[6], (const float*)d_in[7], (const float*)d_in[8],
      (float*)d_out);
}

// Round 6
// 50.967 us; speedup vs baseline: 1.0221x; 1.0221x over previous
//
#include <hip/hip_runtime.h>
#include <hip/hip_bf16.h>
#include <stdint.h>

typedef __attribute__((ext_vector_type(8))) short bf16x8;
typedef __attribute__((ext_vector_type(4))) float f32x4;

static constexpr int B_ROWS = 2097152;
static constexpr int TILES = B_ROWS / 16;            // 131072
static constexpr int BLOCKS = 1024;
static constexpr int WAVES_PER_BLOCK = 4;
static constexpr int TOTAL_WAVES = BLOCKS * WAVES_PER_BLOCK;       // 4096
static constexpr int ITERS = TILES / TOTAL_WAVES;                  // 32

__device__ __forceinline__ short f2bf(float f) {
  union { float f; uint32_t u; } v; v.f = f;
  uint32_t r = v.u + 0x7fffu + ((v.u >> 16) & 1u);   // RNE truncate to bf16
  return (short)(r >> 16);
}
__device__ __forceinline__ uint32_t pk2(float lo, float hi) {
  union { __hip_bfloat162 h; uint32_t u; } v;
  v.h = __float22bfloat162_rn(float2{lo, hi});       // v_cvt_pk_bf16_f32
  return v.u;
}
__device__ __forceinline__ float relu(float x) { return x > 0.f ? x : 0.f; }

// Best-measured variant (R4, 50.76 us = 5.46 TB/s, 87% of copy ceiling):
// Operand-swapped MFMA MLP (batch-row on c, feat on (g,r)); no LDS, no
// transpose; depth-2 prefetch; grid-stride marching-front tile order.
// R5's dense-sector LDS staging regressed (-2.6%) and is reverted.
__global__ __launch_bounds__(256, 4) void colony_mlp(
    const float* __restrict__ x_local, const float* __restrict__ x_all,
    const float* __restrict__ W1, const float* __restrict__ b1,
    const float* __restrict__ W2, const float* __restrict__ b2,
    const float* __restrict__ W3, const float* __restrict__ b3,
    const float* __restrict__ rw, float* __restrict__ out)
{
  const int tid  = threadIdx.x;
  const int wave = tid >> 6;
  const int lane = tid & 63;
  const int c = lane & 15;   // batch-row-in-tile (and weight-fragment col)
  const int g = lane >> 4;   // k-group

  // ---- W1^T fragments (A-operand): w1f[t][j] = W1[k=8g+j][16t+c] ----
  // k=28 slot (g==3,j==4) carries b1; k=29..31 are zero.
  bf16x8 w1f[4];
#pragma unroll
  for (int t = 0; t < 4; ++t)
#pragma unroll
    for (int j = 0; j < 8; ++j) {
      int k = 8 * g + j;
      float v = (k < 28) ? W1[k * 64 + 16 * t + c]
              : (k == 28) ? b1[16 * t + c] : 0.f;
      w1f[t][j] = f2bf(v);
    }
  // ---- W2^T fragments with the layer-2 k-perm: feat = 16*(2ks+(j>>2)) + 4g + (j&3) ----
  bf16x8 w2f[2][2];   // [t2][ks]
#pragma unroll
  for (int t2 = 0; t2 < 2; ++t2)
#pragma unroll
    for (int ks = 0; ks < 2; ++ks)
#pragma unroll
      for (int j = 0; j < 8; ++j) {
        int feat = 16 * (2 * ks + (j >> 2)) + 4 * g + (j & 3);
        w2f[t2][ks][j] = f2bf(W2[feat * 32 + 16 * t2 + c]);
      }
  // per-(g,r) layer-2 bias and layer-3 weights (feat2 = 16t2 + 4g + r)
  float b2v[2][4], w3v[2][4];
#pragma unroll
  for (int t2 = 0; t2 < 2; ++t2)
#pragma unroll
    for (int r = 0; r < 4; ++r) {
      b2v[t2][r] = b2[16 * t2 + 4 * g + r];
      w3v[t2][r] = 0.1f * W3[16 * t2 + 4 * g + r];
    }

  // softmax(|risk_weights|), uniform
  const float e0 = expf(fabsf(rw[0])), e1 = expf(fabsf(rw[1]));
  const float e2 = expf(fabsf(rw[2])), e3 = expf(fabsf(rw[3]));
  const float inv = 1.f / (e0 + e1 + e2 + e3);
  const float sw0 = e0 * inv, sw1 = e1 * inv, sw2 = e2 * inv, sw3 = e3 * inv;
  const float base = 0.3f + 0.1f * b3[0];

  const int wave_id = blockIdx.x * WAVES_PER_BLOCK + wave;   // 0..4095

  // even/odd iteration streams; tiles: even = wave_id + it*4096 (it even),
  // odd = wave_id + it*4096 (it odd). Each stream advances 2*4096 tiles.
  const size_t rowE = (size_t)wave_id * 16 + c;
  const size_t rowO = (size_t)(wave_id + TOTAL_WAVES) * 16 + c;

  const float* paE; const float* paO; ptrdiff_t stA;
  if (g == 0) {
    paE = x_local + rowE * 4;  paO = x_local + rowO * 4;
    stA = (ptrdiff_t)2 * TOTAL_WAVES * 16 * 4;
  } else {
    paE = x_all + rowE * 28 + 8 * g;  paO = x_all + rowO * 28 + 8 * g;
    stA = (ptrdiff_t)2 * TOTAL_WAVES * 16 * 28;
  }
  const int fboff = (g == 0) ? 4 : (g == 3) ? 16 : 8 * g + 4;
  const float* pbE = x_all + rowE * 28 + fboff;
  const float* pbO = x_all + rowO * 28 + fboff;
  const ptrdiff_t stB = (ptrdiff_t)2 * TOTAL_WAVES * 16 * 28;

  f32x4 ca0 = *(const f32x4*)paE, cb0 = *(const f32x4*)pbE;  // iter it
  f32x4 ca1 = *(const f32x4*)paO, cb1 = *(const f32x4*)pbO;  // iter it+1

  auto compute = [&](const f32x4& ca, const f32x4& cb, int tile) {
    // B-operand layer 1: x_flat[row=c][k=8g+j], k=28 slot = 1.0 (bias)
    bf16x8 af;
    uint32_t* au = (uint32_t*)&af;
    au[0] = pk2(ca.x, ca.y);
    au[1] = pk2(ca.z, ca.w);
    au[2] = (g == 3) ? 0x00003F80u : pk2(cb.x, cb.y);
    au[3] = pk2(cb.z, cb.w);

    f32x4 acc[4];
#pragma unroll
    for (int t = 0; t < 4; ++t) {
      f32x4 zero = {0.f, 0.f, 0.f, 0.f};
      acc[t] = __builtin_amdgcn_mfma_f32_16x16x32_bf16(w1f[t], af, zero, 0, 0, 0);
    }
    // in-lane repack: a2[ks][j] = relu(h1[row=c][feat(g,j,ks)])
    bf16x8 a2[2];
#pragma unroll
    for (int ks = 0; ks < 2; ++ks) {
      uint32_t* u = (uint32_t*)&a2[ks];
      u[0] = pk2(relu(acc[2 * ks + 0][0]), relu(acc[2 * ks + 0][1]));
      u[1] = pk2(relu(acc[2 * ks + 0][2]), relu(acc[2 * ks + 0][3]));
      u[2] = pk2(relu(acc[2 * ks + 1][0]), relu(acc[2 * ks + 1][1]));
      u[3] = pk2(relu(acc[2 * ks + 1][2]), relu(acc[2 * ks + 1][3]));
    }
    f32x4 acc2[2];
#pragma unroll
    for (int t2 = 0; t2 < 2; ++t2) {
      f32x4 ci = {b2v[t2][0], b2v[t2][1], b2v[t2][2], b2v[t2][3]};
      ci = __builtin_amdgcn_mfma_f32_16x16x32_bf16(w2f[t2][0], a2[0], ci, 0, 0, 0);
      acc2[t2] = __builtin_amdgcn_mfma_f32_16x16x32_bf16(w2f[t2][1], a2[1], ci, 0, 0, 0);
    }
    float p = 0.f;
#pragma unroll
    for (int t2 = 0; t2 < 2; ++t2)
#pragma unroll
      for (int r = 0; r < 4; ++r)
        p = fmaf(relu(acc2[t2][r]), w3v[t2][r], p);
    p += __shfl_xor(p, 16, 64);
    p += __shfl_xor(p, 32, 64);

    if (lane < 16) {
      float risk = sw0 * ca.x + sw1 * ca.y + sw2 * ca.z + sw3 * ca.w;
      out[(size_t)tile * 16 + lane] = base - risk + p;
    }
  };

  for (int it = 0; it < ITERS; it += 2) {
    // issue prefetch for iterations it+2, it+3 first (4 independent loads)
    if (it + 2 < ITERS) { paE += stA; pbE += stB; }
    f32x4 na0 = *(const f32x4*)paE;
    f32x4 nb0 = *(const f32x4*)pbE;
    if (it + 3 < ITERS) { paO += stA; pbO += stB; }
    f32x4 na1 = *(const f32x4*)paO;
    f32x4 nb1 = *(const f32x4*)pbO;

    compute(ca0, cb0, wave_id + it * TOTAL_WAVES);
    compute(ca1, cb1, wave_id + (it + 1) * TOTAL_WAVES);

    ca0 = na0; cb0 = nb0; ca1 = na1; cb1 = nb1;
  }
}

extern "C" void kernel_launch(void* const* d_in, const int* in_sizes, int n_in,
                              void* d_out, int out_size, void* d_ws, size_t ws_size,
                              hipStream_t stream) {
  colony_mlp<<<dim3(BLOCKS), dim3(256), 0, stream>>>(
      (const float*)d_in[0], (const float*)d_in[1], (const float*)d_in[2],
      (const float*)d_in[3], (const float*)d_in[4], (const float*)d_in[5],
      (const float*)d_in[6], (const float*)d_in[7], (const float*)d_in[8],
      (float*)d_out);
}